// Round 4
// baseline (249.589 us; speedup 1.0000x reference)
//
#include <hip/hip_runtime.h>

// DQNet fused kernel — MI355X (gfx950).
// B=64 groups of 100 nodes; H=64; K=5; A=50 actions; 3 GNN steps; 9900 edges/group.
// Everything is group-local => ONE kernel, one 1024-thread block per group.
// Algebra used (verified in rounds 2-3):
//  - segment_sum over the dense graph == dense matmul n1 = Wt @ h, Wt[j][i]=e1^2*d, diag 0
//  - GNN step 1 has h=0  =>  h1 = relu(base + l2_b) exactly
//  - h2[a0]+h2[a1] == (h[a0]+h[a1])@t7_1_w + 2*t7_1_b
#define HD 64
#define NPG 100
#define NGRP 64
#define NACT 50
#define EPG 9900

typedef const float* fcp;

__global__ __launch_bounds__(1024)
void k_fused(fcp label, fcp e_type, fcp dvec,
             fcp l1_w, fcp l1_b, fcp l2_w, fcp l2_b,
             fcp t3_w, fcp t3_b, fcp t4_w, fcp t4_b,
             fcp t5_w, fcp t5_b, fcp t6_w, fcp t6_b,
             fcp t7_1_w, fcp t7_1_b, fcp t7_2_w, fcp t7_2_b,
             fcp t9_1_w, fcp t9_1_b, fcp t9_2_w, fcp t9_2_b,
             const int* __restrict__ actions,
             float* __restrict__ WtGlob, float* __restrict__ out)
{
    const int g  = blockIdx.x;
    const int t  = threadIdx.x;
    const int hh = t & 63;          // h-dim lane
    const int w  = t >> 6;          // wave 0..15

    // hs: t4s -> h (GNN-resident) -> tail weight staging
    // sb: s_e staging halves -> n1 -> tail activation ping-pong
    __shared__ __align__(16) float hs[NPG * HD];   // 25.6 KB
    __shared__ __align__(16) float sb[NPG * HD];   // 25.6 KB
    __shared__ __align__(16) float awk[16 * HD];   // 4 KB (mean partials / meanl / srelu)
    __shared__ float gbuf[HD];

    float* WtG = WtGlob + g * (NPG * NPG);

    // ------------------- Phase A/B: edges -> Wt (global) + t4 sums -------------------
    const float w4  = t4_w[hh];
    const float b4  = t4_b[hh];
    const float rb4 = fmaxf(b4, 0.f);          // spurious diagonal relu(b4) term
    const int ebase = g * EPG;

    for (int half = 0; half < 2; ++half) {
        const int j0 = half * 50;
        // stage s_e[jl][i] into sb; write Wt[j][i] coalesced to global
        for (int idx = t; idx < 50 * NPG; idx += 1024) {
            const int jl = idx / NPG;
            const int i  = idx - jl * NPG;
            const int j  = j0 + jl;
            float s = 0.f, wv = 0.f;
            if (i != j) {
                const int e   = ebase + i * 99 + j - (j > i ? 1 : 0);
                const float e1 = e_type[2 * e];
                const float dd = dvec[e];
                s  = dd * e1;
                wv = e1 * e1 * dd;
            }
            sb[idx] = s;
            WtG[j0 * NPG + idx] = wv;
        }
        __syncthreads();
        // t4s[j][hh] for this half's j (wave-strided), b128 broadcasts of s_e
        for (int j = w; j < NPG; j += 16) {
            if (j < j0 || j >= j0 + 50) continue;
            const int jl = j - j0;
            float acc = -rb4;
            #pragma unroll 5
            for (int ib = 0; ib < 25; ++ib) {
                const float4 s4 = *(const float4*)&sb[jl * NPG + 4 * ib];
                acc += fmaxf(s4.x * w4 + b4, 0.f);
                acc += fmaxf(s4.y * w4 + b4, 0.f);
                acc += fmaxf(s4.z * w4 + b4, 0.f);
                acc += fmaxf(s4.w * w4 + b4, 0.f);
            }
            hs[j * HD + hh] = acc;            // hs holds t4s for now
        }
        __syncthreads();
    }

    // ------------------- Phase E: base in registers -------------------
    float l1w_r[5];
    #pragma unroll
    for (int k = 0; k < 5; ++k) l1w_r[k] = l1_w[k * HD + hh];
    const float bsum = l1_b[hh] + t3_b[hh];
    const float l2bv = l2_b[hh];

    float base_r[7];
    #pragma unroll
    for (int k = 0; k < 7; ++k) {
        const int j = w + 16 * k;
        float v = bsum;
        if (j < NPG) {
            #pragma unroll
            for (int kk = 0; kk < 5; ++kk)
                v += label[(g * NPG + j) * 5 + kk] * l1w_r[kk];
        }
        base_r[k] = v;
    }
    // base += t4s @ t3_w   (q-outer: weights coalesced+reused, t4s b128 bcast)
    for (int qb = 0; qb < 16; ++qb) {
        const float wt0 = t3_w[(4*qb+0) * HD + hh];
        const float wt1 = t3_w[(4*qb+1) * HD + hh];
        const float wt2 = t3_w[(4*qb+2) * HD + hh];
        const float wt3 = t3_w[(4*qb+3) * HD + hh];
        #pragma unroll
        for (int k = 0; k < 7; ++k) {
            const int j = w + 16 * k;
            if (j < NPG) {
                const float4 x4 = *(const float4*)&hs[j * HD + 4 * qb];
                base_r[k] += x4.x*wt0 + x4.y*wt1 + x4.z*wt2 + x4.w*wt3;
            }
        }
    }
    __syncthreads();              // t4s fully consumed
    // Phase F: h1 = relu(base + l2_b)   (GNN step 1, n1 == 0)
    #pragma unroll
    for (int k = 0; k < 7; ++k) {
        const int j = w + 16 * k;
        if (j < NPG) hs[j * HD + hh] = fmaxf(base_r[k] + l2bv, 0.f);
    }
    __syncthreads();

    // ------------------- GNN steps 2,3 -------------------
    for (int step = 0; step < 2; ++step) {
        // n1[j][hh] = sum_i Wt[j][i]*h[i][hh] ; Wt via uniform float4 L2 loads
        float acc[7];
        #pragma unroll
        for (int k = 0; k < 7; ++k) acc[k] = 0.f;
        for (int ib = 0; ib < 25; ++ib) {
            const float h0 = hs[(4*ib+0) * HD + hh];
            const float h1 = hs[(4*ib+1) * HD + hh];
            const float h2 = hs[(4*ib+2) * HD + hh];
            const float h3 = hs[(4*ib+3) * HD + hh];
            #pragma unroll
            for (int k = 0; k < 7; ++k) {
                const int j = w + 16 * k;
                if (j < NPG) {
                    const float4 wv = *(const float4*)&WtG[j * NPG + 4 * ib];
                    acc[k] += wv.x*h0 + wv.y*h1 + wv.z*h2 + wv.w*h3;
                }
            }
        }
        #pragma unroll
        for (int k = 0; k < 7; ++k) {
            const int j = w + 16 * k;
            if (j < NPG) sb[j * HD + hh] = acc[k];   // n1
        }
        __syncthreads();          // all hs reads done before hs rewrite
        // h' = relu(base + n1 @ l2_w + l2_b)
        float hn[7];
        #pragma unroll
        for (int k = 0; k < 7; ++k) hn[k] = base_r[k] + l2bv;
        for (int qb = 0; qb < 16; ++qb) {
            const float wt0 = l2_w[(4*qb+0) * HD + hh];
            const float wt1 = l2_w[(4*qb+1) * HD + hh];
            const float wt2 = l2_w[(4*qb+2) * HD + hh];
            const float wt3 = l2_w[(4*qb+3) * HD + hh];
            #pragma unroll
            for (int k = 0; k < 7; ++k) {
                const int j = w + 16 * k;
                if (j < NPG) {
                    const float4 x4 = *(const float4*)&sb[j * HD + 4 * qb];
                    hn[k] += x4.x*wt0 + x4.y*wt1 + x4.z*wt2 + x4.w*wt3;
                }
            }
        }
        #pragma unroll
        for (int k = 0; k < 7; ++k) {
            const int j = w + 16 * k;
            if (j < NPG) hs[j * HD + hh] = fmaxf(hn[k], 0.f);
        }
        __syncthreads();
    }

    // ------------------- Tail -------------------
    // action indices early (uniform loads, latency hidden)
    int a0r[4], a1r[4];
    #pragma unroll
    for (int k = 0; k < 4; ++k) {
        const int a = w + 16 * k;
        a0r[k] = a1r[k] = 0;
        if (a < NACT) {
            a0r[k] = actions[(g * NACT + a) * 2 + 0];
            a1r[k] = actions[(g * NACT + a) * 2 + 1];
        }
    }
    // mean partials over this wave's j-set
    {
        float m = 0.f;
        #pragma unroll
        for (int k = 0; k < 7; ++k) {
            const int j = w + 16 * k;
            if (j < NPG) m += hs[j * HD + hh];
        }
        awk[w * HD + hh] = m;
    }
    // ha = h[a0]+h[a1] -> sb rows [0,50)
    #pragma unroll
    for (int k = 0; k < 4; ++k) {
        const int a = w + 16 * k;
        if (a < NACT)
            sb[a * HD + hh] = hs[a0r[k] * HD + hh] + hs[a1r[k] * HD + hh];
    }
    __syncthreads();

    // stage t7_1_w into hs (hs dead); wave 0 computes gb = t9_1(relu(t6(mean)))
    for (int idx = t; idx < HD * HD; idx += 1024) hs[idx] = t7_1_w[idx];
    if (t < HD) {
        float m = 0.f;
        #pragma unroll
        for (int ww = 0; ww < 16; ++ww) m += awk[ww * HD + t];
        awk[t] = m * (1.f / NPG);                       // meanl (row 0)
    }
    if (t < HD) {
        float s = t6_b[t];
        #pragma unroll 8
        for (int q = 0; q < HD; ++q) s += awk[q] * t6_w[q * HD + t];
        awk[HD + t] = fmaxf(s, 0.f);                    // srelu (row 1)
    }
    if (t < HD) {
        float s = t9_1_b[t];
        #pragma unroll 8
        for (int q = 0; q < HD; ++q) s += awk[HD + q] * t9_1_w[q * HD + t];
        gbuf[t] = s;
    }
    __syncthreads();

    // r1 = relu(ha @ t7_1_w + 2*b71) : sb[0,50) -> sb[50,100)
    {
        const float b71 = 2.f * t7_1_b[hh];
        float r[4];
        #pragma unroll
        for (int k = 0; k < 4; ++k) r[k] = b71;
        for (int qb = 0; qb < 16; ++qb) {
            const float wt0 = hs[(4*qb+0)*HD + hh];
            const float wt1 = hs[(4*qb+1)*HD + hh];
            const float wt2 = hs[(4*qb+2)*HD + hh];
            const float wt3 = hs[(4*qb+3)*HD + hh];
            #pragma unroll
            for (int k = 0; k < 4; ++k) {
                const int a = w + 16 * k;
                if (a < NACT) {
                    const float4 x4 = *(const float4*)&sb[a * HD + 4*qb];
                    r[k] += x4.x*wt0 + x4.y*wt1 + x4.z*wt2 + x4.w*wt3;
                }
            }
        }
        #pragma unroll
        for (int k = 0; k < 4; ++k) {
            const int a = w + 16 * k;
            if (a < NACT) sb[(NACT + a) * HD + hh] = fmaxf(r[k], 0.f);
        }
    }
    __syncthreads();
    for (int idx = t; idx < HD * HD; idx += 1024) hs[idx] = t7_2_w[idx];
    __syncthreads();

    // r2 = relu(r1 @ t7_2_w + b72) : sb[50,100) -> sb[0,50)
    {
        const float b72 = t7_2_b[hh];
        float r[4];
        #pragma unroll
        for (int k = 0; k < 4; ++k) r[k] = b72;
        for (int qb = 0; qb < 16; ++qb) {
            const float wt0 = hs[(4*qb+0)*HD + hh];
            const float wt1 = hs[(4*qb+1)*HD + hh];
            const float wt2 = hs[(4*qb+2)*HD + hh];
            const float wt3 = hs[(4*qb+3)*HD + hh];
            #pragma unroll
            for (int k = 0; k < 4; ++k) {
                const int a = w + 16 * k;
                if (a < NACT) {
                    const float4 x4 = *(const float4*)&sb[(NACT + a) * HD + 4*qb];
                    r[k] += x4.x*wt0 + x4.y*wt1 + x4.z*wt2 + x4.w*wt3;
                }
            }
        }
        #pragma unroll
        for (int k = 0; k < 4; ++k) {
            const int a = w + 16 * k;
            if (a < NACT) sb[a * HD + hh] = fmaxf(r[k], 0.f);
        }
    }
    __syncthreads();
    for (int idx = t; idx < HD * HD; idx += 1024) hs[idx] = t9_2_w[idx];
    __syncthreads();

    // u = r2 @ t9_2_w + b92 ; q = relu(gb+u) ; Q = q.t5_w + t5_b
    {
        const float b92  = t9_2_b[hh];
        const float t5wv = t5_w[hh];
        const float t5bv = t5_b[0];
        const float gbv  = gbuf[hh];
        float u[4];
        #pragma unroll
        for (int k = 0; k < 4; ++k) u[k] = b92;
        for (int qb = 0; qb < 16; ++qb) {
            const float wt0 = hs[(4*qb+0)*HD + hh];
            const float wt1 = hs[(4*qb+1)*HD + hh];
            const float wt2 = hs[(4*qb+2)*HD + hh];
            const float wt3 = hs[(4*qb+3)*HD + hh];
            #pragma unroll
            for (int k = 0; k < 4; ++k) {
                const int a = w + 16 * k;
                if (a < NACT) {
                    const float4 x4 = *(const float4*)&sb[a * HD + 4*qb];
                    u[k] += x4.x*wt0 + x4.y*wt1 + x4.z*wt2 + x4.w*wt3;
                }
            }
        }
        #pragma unroll
        for (int k = 0; k < 4; ++k) {
            const int a = w + 16 * k;
            float qv = fmaxf(gbv + u[k], 0.f) * t5wv;
            #pragma unroll
            for (int off = 32; off > 0; off >>= 1) qv += __shfl_xor(qv, off, 64);
            if (a < NACT && hh == 0) out[g * NACT + a] = qv + t5bv;
        }
    }
}

// ---------------------------------------------------------------------------
extern "C" void kernel_launch(void* const* d_in, const int* in_sizes, int n_in,
                              void* d_out, int out_size, void* d_ws, size_t ws_size,
                              hipStream_t stream)
{
    fcp label  = (fcp)d_in[0];
    fcp e_type = (fcp)d_in[1];
    fcp dvec   = (fcp)d_in[2];
    fcp l1_w   = (fcp)d_in[3];
    fcp l1_b   = (fcp)d_in[4];
    fcp l2_w   = (fcp)d_in[5];
    fcp l2_b   = (fcp)d_in[6];
    fcp t3_w   = (fcp)d_in[7];
    fcp t3_b   = (fcp)d_in[8];
    fcp t4_w   = (fcp)d_in[9];
    fcp t4_b   = (fcp)d_in[10];
    fcp t5_w   = (fcp)d_in[11];
    fcp t5_b   = (fcp)d_in[12];
    fcp t6_w   = (fcp)d_in[13];
    fcp t6_b   = (fcp)d_in[14];
    fcp t7_1_w = (fcp)d_in[15];
    fcp t7_1_b = (fcp)d_in[16];
    fcp t7_2_w = (fcp)d_in[17];
    fcp t7_2_b = (fcp)d_in[18];
    fcp t9_1_w = (fcp)d_in[19];
    fcp t9_1_b = (fcp)d_in[20];
    fcp t9_2_w = (fcp)d_in[21];
    fcp t9_2_b = (fcp)d_in[22];
    // d_in[23]=src, d_in[24]=dst  -- topology derived analytically
    const int* actions = (const int*)d_in[25];

    float* Wt = (float*)d_ws;   // 64*100*100 f32 = 2.56 MB

    k_fused<<<dim3(NGRP), dim3(1024), 0, stream>>>(
        label, e_type, dvec, l1_w, l1_b, l2_w, l2_b, t3_w, t3_b, t4_w, t4_b,
        t5_w, t5_b, t6_w, t6_b, t7_1_w, t7_1_b, t7_2_w, t7_2_b,
        t9_1_w, t9_1_b, t9_2_w, t9_2_b, actions, Wt, (float*)d_out);
}

// Round 5
// 248.065 us; speedup vs baseline: 1.0061x; 1.0061x over previous
//
#include <hip/hip_runtime.h>

// DQNet fused kernel — MI355X (gfx950).
// B=64 groups of 100 nodes; H=64; K=5; A=50 actions; 3 GNN steps; 9900 edges/group.
// Everything is group-local => ONE kernel, one 1024-thread block per group.
// Algebra (verified rounds 2-4):
//  - segment_sum over dense graph == dense matmul n1 = Wt @ h, Wt[j][i]=e1^2*d, diag 0
//  - GNN step 1 has h=0  =>  h1 = relu(base + l2_b) exactly
//  - h2[a0]+h2[a1] == (h[a0]+h[a1])@t7_1_w + 2*t7_1_b
// Round-5 fixes: coalesced edge loads (i-outer/jl-inner identity LDS map),
// Wt transpose via LDS, launch_bounds(1024,4) for 128-VGPR pipelining.
#define HD 64
#define NPG 100
#define NGRP 64
#define NACT 50
#define EPG 9900

typedef const float* fcp;

__global__ __launch_bounds__(1024, 4)
void k_fused(fcp label, fcp e_type, fcp dvec,
             fcp l1_w, fcp l1_b, fcp l2_w, fcp l2_b,
             fcp t3_w, fcp t3_b, fcp t4_w, fcp t4_b,
             fcp t5_w, fcp t5_b, fcp t6_w, fcp t6_b,
             fcp t7_1_w, fcp t7_1_b, fcp t7_2_w, fcp t7_2_b,
             fcp t9_1_w, fcp t9_1_b, fcp t9_2_w, fcp t9_2_b,
             const int* __restrict__ actions,
             float* __restrict__ WtGlob, float* __restrict__ out)
{
    const int g  = blockIdx.x;
    const int t  = threadIdx.x;
    const int hh = t & 63;          // h-dim lane
    const int w  = t >> 6;          // wave 0..15

    // hs: t4s -> h (GNN-resident) -> tail weight staging
    // sb: edge staging (s_ld/w_ld) -> n1 -> tail activation ping-pong
    __shared__ __align__(16) float hs[NPG * HD];   // 25.6 KB
    __shared__ __align__(16) float sb[NPG * HD];   // 25.6 KB
    __shared__ __align__(16) float awk[16 * HD];   // 4 KB (mean partials / meanl / srelu)
    __shared__ float gbuf[HD];

    float* WtG = WtGlob + g * (NPG * NPG);

    // ------------- Phase A/B: edges -> t4 sums (hs) + Wt (global, via LDS transpose)
    const float w4  = t4_w[hh];
    const float b4  = t4_b[hh];
    const float rb4 = fmaxf(b4, 0.f);          // spurious diagonal relu(b4) term
    const int ebase = g * EPG;
    float* s_ld = sb;            // 2500 floats, layout idx = i*25 + jl
    float* w_ld = sb + 2500;     // 2500 floats, same layout

    for (int c = 0; c < 4; ++c) {
        const int j0 = c * 25;
        // coalesced: consecutive t -> consecutive jl (fixed i) -> consecutive e
        for (int idx = t; idx < 2500; idx += 1024) {
            const int i  = idx / 25;
            const int jl = idx - i * 25;
            const int j  = j0 + jl;
            float s = 0.f, wv = 0.f;
            if (i != j) {
                const int e   = ebase + i * 99 + j - (j > i ? 1 : 0);
                const float e1 = e_type[2 * e];
                const float dd = dvec[e];
                s  = dd * e1;
                wv = e1 * e1 * dd;
            }
            s_ld[idx] = s;       // identity map: stride-1 LDS store
            w_ld[idx] = wv;
        }
        __syncthreads();
        // t4 sums: wave-uniform broadcast reads, 4 partial accumulators
        for (int jl = w; jl < 25; jl += 16) {
            float a0 = 0.f, a1 = 0.f, a2 = 0.f, a3 = 0.f;
            #pragma unroll 5
            for (int ib = 0; ib < 25; ++ib) {
                a0 += fmaxf(s_ld[(4*ib+0)*25 + jl] * w4 + b4, 0.f);
                a1 += fmaxf(s_ld[(4*ib+1)*25 + jl] * w4 + b4, 0.f);
                a2 += fmaxf(s_ld[(4*ib+2)*25 + jl] * w4 + b4, 0.f);
                a3 += fmaxf(s_ld[(4*ib+3)*25 + jl] * w4 + b4, 0.f);
            }
            hs[(j0 + jl) * HD + hh] = (a0 + a1) + (a2 + a3) - rb4;
        }
        // Wt[j][i] global write, coalesced; LDS read stride 25 (gcd(25,32)=1 -> free)
        for (int idx = t; idx < 2500; idx += 1024) {
            const int jl = idx / 100;
            const int i  = idx - jl * 100;
            WtG[(j0 + jl) * NPG + i] = w_ld[i * 25 + jl];
        }
        __syncthreads();
    }

    // ------------------- Phase E: base in registers -------------------
    float l1w_r[5];
    #pragma unroll
    for (int k = 0; k < 5; ++k) l1w_r[k] = l1_w[k * HD + hh];
    const float bsum = l1_b[hh] + t3_b[hh];
    const float l2bv = l2_b[hh];

    float base_r[7];
    #pragma unroll
    for (int k = 0; k < 7; ++k) {
        const int j = w + 16 * k;
        float v = bsum;
        if (j < NPG) {
            #pragma unroll
            for (int kk = 0; kk < 5; ++kk)
                v += label[(g * NPG + j) * 5 + kk] * l1w_r[kk];
        }
        base_r[k] = v;
    }
    // base += t4s @ t3_w   (q-outer: weights coalesced+reused, t4s b128 bcast)
    for (int qb = 0; qb < 16; ++qb) {
        const float wt0 = t3_w[(4*qb+0) * HD + hh];
        const float wt1 = t3_w[(4*qb+1) * HD + hh];
        const float wt2 = t3_w[(4*qb+2) * HD + hh];
        const float wt3 = t3_w[(4*qb+3) * HD + hh];
        #pragma unroll
        for (int k = 0; k < 7; ++k) {
            const int j = w + 16 * k;
            if (j < NPG) {
                const float4 x4 = *(const float4*)&hs[j * HD + 4 * qb];
                base_r[k] += x4.x*wt0 + x4.y*wt1 + x4.z*wt2 + x4.w*wt3;
            }
        }
    }
    __syncthreads();              // t4s fully consumed
    // Phase F: h1 = relu(base + l2_b)   (GNN step 1, n1 == 0)
    #pragma unroll
    for (int k = 0; k < 7; ++k) {
        const int j = w + 16 * k;
        if (j < NPG) hs[j * HD + hh] = fmaxf(base_r[k] + l2bv, 0.f);
    }
    __syncthreads();

    // ------------------- GNN steps 2,3 -------------------
    for (int step = 0; step < 2; ++step) {
        // n1[j][hh] = sum_i Wt[j][i]*h[i][hh] ; Wt via uniform float4 L2 loads
        float acc[7];
        #pragma unroll
        for (int k = 0; k < 7; ++k) acc[k] = 0.f;
        for (int ib = 0; ib < 25; ++ib) {
            const float h0 = hs[(4*ib+0) * HD + hh];
            const float h1 = hs[(4*ib+1) * HD + hh];
            const float h2 = hs[(4*ib+2) * HD + hh];
            const float h3 = hs[(4*ib+3) * HD + hh];
            #pragma unroll
            for (int k = 0; k < 7; ++k) {
                const int j = w + 16 * k;
                if (j < NPG) {
                    const float4 wv = *(const float4*)&WtG[j * NPG + 4 * ib];
                    acc[k] += wv.x*h0 + wv.y*h1 + wv.z*h2 + wv.w*h3;
                }
            }
        }
        #pragma unroll
        for (int k = 0; k < 7; ++k) {
            const int j = w + 16 * k;
            if (j < NPG) sb[j * HD + hh] = acc[k];   // n1
        }
        __syncthreads();          // all hs reads done before hs rewrite
        // h' = relu(base + n1 @ l2_w + l2_b)
        float hn[7];
        #pragma unroll
        for (int k = 0; k < 7; ++k) hn[k] = base_r[k] + l2bv;
        for (int qb = 0; qb < 16; ++qb) {
            const float wt0 = l2_w[(4*qb+0) * HD + hh];
            const float wt1 = l2_w[(4*qb+1) * HD + hh];
            const float wt2 = l2_w[(4*qb+2) * HD + hh];
            const float wt3 = l2_w[(4*qb+3) * HD + hh];
            #pragma unroll
            for (int k = 0; k < 7; ++k) {
                const int j = w + 16 * k;
                if (j < NPG) {
                    const float4 x4 = *(const float4*)&sb[j * HD + 4 * qb];
                    hn[k] += x4.x*wt0 + x4.y*wt1 + x4.z*wt2 + x4.w*wt3;
                }
            }
        }
        #pragma unroll
        for (int k = 0; k < 7; ++k) {
            const int j = w + 16 * k;
            if (j < NPG) hs[j * HD + hh] = fmaxf(hn[k], 0.f);
        }
        __syncthreads();
    }

    // ------------------- Tail -------------------
    // action indices early (uniform loads, latency hidden)
    int a0r[4], a1r[4];
    #pragma unroll
    for (int k = 0; k < 4; ++k) {
        const int a = w + 16 * k;
        a0r[k] = a1r[k] = 0;
        if (a < NACT) {
            a0r[k] = actions[(g * NACT + a) * 2 + 0];
            a1r[k] = actions[(g * NACT + a) * 2 + 1];
        }
    }
    // mean partials over this wave's j-set
    {
        float m = 0.f;
        #pragma unroll
        for (int k = 0; k < 7; ++k) {
            const int j = w + 16 * k;
            if (j < NPG) m += hs[j * HD + hh];
        }
        awk[w * HD + hh] = m;
    }
    // ha = h[a0]+h[a1] -> sb rows [0,50)
    #pragma unroll
    for (int k = 0; k < 4; ++k) {
        const int a = w + 16 * k;
        if (a < NACT)
            sb[a * HD + hh] = hs[a0r[k] * HD + hh] + hs[a1r[k] * HD + hh];
    }
    __syncthreads();

    // stage t7_1_w into hs (hs dead); wave 0 computes gb = t9_1(relu(t6(mean)))
    for (int idx = t; idx < HD * HD; idx += 1024) hs[idx] = t7_1_w[idx];
    if (t < HD) {
        float m = 0.f;
        #pragma unroll
        for (int ww = 0; ww < 16; ++ww) m += awk[ww * HD + t];
        awk[t] = m * (1.f / NPG);                       // meanl (row 0)
    }
    if (t < HD) {
        float s = t6_b[t];
        #pragma unroll 8
        for (int q = 0; q < HD; ++q) s += awk[q] * t6_w[q * HD + t];
        awk[HD + t] = fmaxf(s, 0.f);                    // srelu (row 1)
    }
    if (t < HD) {
        float s = t9_1_b[t];
        #pragma unroll 8
        for (int q = 0; q < HD; ++q) s += awk[HD + q] * t9_1_w[q * HD + t];
        gbuf[t] = s;
    }
    __syncthreads();

    // r1 = relu(ha @ t7_1_w + 2*b71) : sb[0,50) -> sb[50,100)
    {
        const float b71 = 2.f * t7_1_b[hh];
        float r[4];
        #pragma unroll
        for (int k = 0; k < 4; ++k) r[k] = b71;
        for (int qb = 0; qb < 16; ++qb) {
            const float wt0 = hs[(4*qb+0)*HD + hh];
            const float wt1 = hs[(4*qb+1)*HD + hh];
            const float wt2 = hs[(4*qb+2)*HD + hh];
            const float wt3 = hs[(4*qb+3)*HD + hh];
            #pragma unroll
            for (int k = 0; k < 4; ++k) {
                const int a = w + 16 * k;
                if (a < NACT) {
                    const float4 x4 = *(const float4*)&sb[a * HD + 4*qb];
                    r[k] += x4.x*wt0 + x4.y*wt1 + x4.z*wt2 + x4.w*wt3;
                }
            }
        }
        #pragma unroll
        for (int k = 0; k < 4; ++k) {
            const int a = w + 16 * k;
            if (a < NACT) sb[(NACT + a) * HD + hh] = fmaxf(r[k], 0.f);
        }
    }
    __syncthreads();
    for (int idx = t; idx < HD * HD; idx += 1024) hs[idx] = t7_2_w[idx];
    __syncthreads();

    // r2 = relu(r1 @ t7_2_w + b72) : sb[50,100) -> sb[0,50)
    {
        const float b72 = t7_2_b[hh];
        float r[4];
        #pragma unroll
        for (int k = 0; k < 4; ++k) r[k] = b72;
        for (int qb = 0; qb < 16; ++qb) {
            const float wt0 = hs[(4*qb+0)*HD + hh];
            const float wt1 = hs[(4*qb+1)*HD + hh];
            const float wt2 = hs[(4*qb+2)*HD + hh];
            const float wt3 = hs[(4*qb+3)*HD + hh];
            #pragma unroll
            for (int k = 0; k < 4; ++k) {
                const int a = w + 16 * k;
                if (a < NACT) {
                    const float4 x4 = *(const float4*)&sb[(NACT + a) * HD + 4*qb];
                    r[k] += x4.x*wt0 + x4.y*wt1 + x4.z*wt2 + x4.w*wt3;
                }
            }
        }
        #pragma unroll
        for (int k = 0; k < 4; ++k) {
            const int a = w + 16 * k;
            if (a < NACT) sb[a * HD + hh] = fmaxf(r[k], 0.f);
        }
    }
    __syncthreads();
    for (int idx = t; idx < HD * HD; idx += 1024) hs[idx] = t9_2_w[idx];
    __syncthreads();

    // u = r2 @ t9_2_w + b92 ; q = relu(gb+u) ; Q = q.t5_w + t5_b
    {
        const float b92  = t9_2_b[hh];
        const float t5wv = t5_w[hh];
        const float t5bv = t5_b[0];
        const float gbv  = gbuf[hh];
        float u[4];
        #pragma unroll
        for (int k = 0; k < 4; ++k) u[k] = b92;
        for (int qb = 0; qb < 16; ++qb) {
            const float wt0 = hs[(4*qb+0)*HD + hh];
            const float wt1 = hs[(4*qb+1)*HD + hh];
            const float wt2 = hs[(4*qb+2)*HD + hh];
            const float wt3 = hs[(4*qb+3)*HD + hh];
            #pragma unroll
            for (int k = 0; k < 4; ++k) {
                const int a = w + 16 * k;
                if (a < NACT) {
                    const float4 x4 = *(const float4*)&sb[a * HD + 4*qb];
                    u[k] += x4.x*wt0 + x4.y*wt1 + x4.z*wt2 + x4.w*wt3;
                }
            }
        }
        #pragma unroll
        for (int k = 0; k < 4; ++k) {
            const int a = w + 16 * k;
            float qv = fmaxf(gbv + u[k], 0.f) * t5wv;
            #pragma unroll
            for (int off = 32; off > 0; off >>= 1) qv += __shfl_xor(qv, off, 64);
            if (a < NACT && hh == 0) out[g * NACT + a] = qv + t5bv;
        }
    }
}

// ---------------------------------------------------------------------------
extern "C" void kernel_launch(void* const* d_in, const int* in_sizes, int n_in,
                              void* d_out, int out_size, void* d_ws, size_t ws_size,
                              hipStream_t stream)
{
    fcp label  = (fcp)d_in[0];
    fcp e_type = (fcp)d_in[1];
    fcp dvec   = (fcp)d_in[2];
    fcp l1_w   = (fcp)d_in[3];
    fcp l1_b   = (fcp)d_in[4];
    fcp l2_w   = (fcp)d_in[5];
    fcp l2_b   = (fcp)d_in[6];
    fcp t3_w   = (fcp)d_in[7];
    fcp t3_b   = (fcp)d_in[8];
    fcp t4_w   = (fcp)d_in[9];
    fcp t4_b   = (fcp)d_in[10];
    fcp t5_w   = (fcp)d_in[11];
    fcp t5_b   = (fcp)d_in[12];
    fcp t6_w   = (fcp)d_in[13];
    fcp t6_b   = (fcp)d_in[14];
    fcp t7_1_w = (fcp)d_in[15];
    fcp t7_1_b = (fcp)d_in[16];
    fcp t7_2_w = (fcp)d_in[17];
    fcp t7_2_b = (fcp)d_in[18];
    fcp t9_1_w = (fcp)d_in[19];
    fcp t9_1_b = (fcp)d_in[20];
    fcp t9_2_w = (fcp)d_in[21];
    fcp t9_2_b = (fcp)d_in[22];
    // d_in[23]=src, d_in[24]=dst  -- topology derived analytically
    const int* actions = (const int*)d_in[25];

    float* Wt = (float*)d_ws;   // 64*100*100 f32 = 2.56 MB

    k_fused<<<dim3(NGRP), dim3(1024), 0, stream>>>(
        label, e_type, dvec, l1_w, l1_b, l2_w, l2_b, t3_w, t3_b, t4_w, t4_b,
        t5_w, t5_b, t6_w, t6_b, t7_1_w, t7_1_b, t7_2_w, t7_2_b,
        t9_1_w, t9_1_b, t9_2_w, t9_2_b, actions, Wt, (float*)d_out);
}